// Round 1
// baseline (408.680 us; speedup 1.0000x reference)
//
#include <hip/hip_runtime.h>

// GAT layer: B=4, N=2048, IN_DIM=128, H=4, D=64
// out[b,n,h*D+d] = sum_j softmax_j(mask(leaky(e_src[bh,i]+e_dst[bh,j]))) * h[bh,j,d]
//
// Round 0: correctness-first fp32.
//  Kernel A: h = x @ W.T  -> ws layout [bh][n][d]; e_src/e_dst via wave reduce.
//  Kernel C: fused mask+exp+softmax+PV per (bh, 16-row tile). No max-subtraction
//  needed: scores bounded (~|s|<3) by construction, exp(s) safe in fp32.

#define BDIM 4
#define NDIM 2048
#define INDIM 128
#define HDIM 4
#define DDIM 64
#define BH (BDIM*HDIM)
#define NEG_SLOPE 0.2f

#define TI 16
#define TJ 64
#define PJ 68   // padded p-tile row (floats): breaks bank aliasing, keeps 16B align

// ---------------- Kernel A: linear + attention projections ----------------
__global__ __launch_bounds__(256) void gat_linear(
    const float* __restrict__ x, const float* __restrict__ W,
    const float* __restrict__ att_src, const float* __restrict__ att_dst,
    float* __restrict__ h_ws, float* __restrict__ es_ws, float* __restrict__ ed_ws)
{
    const int bn = blockIdx.x;          // b*N + n
    const int b  = bn >> 11;            // /2048
    const int n  = bn & (NDIM - 1);
    const int t  = threadIdx.x;         // output channel o = head*64 + d

    __shared__ float xs[INDIM];
    if (t < INDIM / 4) {
        ((float4*)xs)[t] = ((const float4*)(x + (size_t)bn * INDIM))[t];
    }
    __syncthreads();

    const float4* wrow = (const float4*)(W + (size_t)t * INDIM);
    float acc = 0.f;
    #pragma unroll 8
    for (int k4 = 0; k4 < INDIM / 4; ++k4) {
        float4 w  = wrow[k4];
        float4 xv = ((const float4*)xs)[k4];
        acc += w.x * xv.x + w.y * xv.y + w.z * xv.z + w.w * xv.w;
    }

    const int head = t >> 6;
    const int d    = t & 63;
    const int bh   = b * HDIM + head;
    h_ws[((size_t)bh * NDIM + n) * DDIM + d] = acc;

    float ps = acc * att_src[t];
    float pd = acc * att_dst[t];
    #pragma unroll
    for (int off = 32; off > 0; off >>= 1) {
        ps += __shfl_down(ps, off, 64);
        pd += __shfl_down(pd, off, 64);
    }
    if (d == 0) {
        es_ws[bh * NDIM + n] = ps;
        ed_ws[bh * NDIM + n] = pd;
    }
}

// ---------------- Kernel C: fused mask + exp + softmax + PV ----------------
__global__ __launch_bounds__(256) void gat_attn(
    const int* __restrict__ adj,
    const float* __restrict__ h_ws, const float* __restrict__ es_ws,
    const float* __restrict__ ed_ws, float* __restrict__ out)
{
    const int blk = blockIdx.x;          // bh * (N/TI) + it
    const int bh  = blk >> 7;            // N/TI = 128
    const int it  = blk & 127;
    const int i0  = it * TI;
    const int t   = threadIdx.x;
    const int il  = t >> 4;              // local row 0..15
    const int dg  = t & 15;              // d-group: d = dg*4 .. dg*4+3

    __shared__ float hs[TJ][DDIM];       // 16 KB
    __shared__ float ps[TI][PJ];         // ~4.3 KB, padded rows
    __shared__ float eds[NDIM];          // 8 KB: e_dst row for this bh
    __shared__ float ess[TI];

    // stage e_dst (whole row) + e_src (tile) once per block
    for (int q = t; q < NDIM / 4; q += 256)
        ((float4*)eds)[q] = ((const float4*)(ed_ws + bh * NDIM))[q];
    if (t < TI) ess[t] = es_ws[bh * NDIM + i0 + t];
    __syncthreads();

    const float es_i  = ess[il];
    const int i_glob  = i0 + il;
    const int* adjrow = adj + (size_t)i_glob * NDIM;

    float a0 = 0.f, a1 = 0.f, a2 = 0.f, a3 = 0.f, l = 0.f;

    for (int j0 = 0; j0 < NDIM; j0 += TJ) {
        // stage h tile [TJ][D]: 1024 float4s, 4 per thread, coalesced
        #pragma unroll
        for (int r = 0; r < 4; ++r) {
            int q  = t + r * 256;        // float4 index
            int j  = q >> 4;
            int dq = q & 15;
            *(float4*)&hs[j][dq * 4] =
                *(const float4*)(h_ws + ((size_t)bh * NDIM + j0 + j) * DDIM + dq * 4);
        }
        // compute p tile: thread handles row il, cols jc..jc+3
        {
            const int jc = dg * 4;
            int4   av = *(const int4*)(adjrow + j0 + jc);
            float4 ev = *(const float4*)&eds[j0 + jc];
            float4 pv;
            float s;
            s = es_i + ev.x; s = s > 0.f ? s : NEG_SLOPE * s; pv.x = (av.x > 0) ? __expf(s) : 0.f;
            s = es_i + ev.y; s = s > 0.f ? s : NEG_SLOPE * s; pv.y = (av.y > 0) ? __expf(s) : 0.f;
            s = es_i + ev.z; s = s > 0.f ? s : NEG_SLOPE * s; pv.z = (av.z > 0) ? __expf(s) : 0.f;
            s = es_i + ev.w; s = s > 0.f ? s : NEG_SLOPE * s; pv.w = (av.w > 0) ? __expf(s) : 0.f;
            *(float4*)&ps[il][jc] = pv;
        }
        __syncthreads();

        // PV accumulate: out[il][dg*4..+3] += p[il][j] * h[j][...]
        #pragma unroll 16
        for (int j = 0; j < TJ; ++j) {
            float  p  = ps[il][j];
            float4 hv = *(const float4*)&hs[j][dg * 4];
            a0 += p * hv.x;
            a1 += p * hv.y;
            a2 += p * hv.z;
            a3 += p * hv.w;
            l  += p;
        }
        __syncthreads();
    }

    const float inv = 1.f / l;
    const int head = bh & 3;
    const int b    = bh >> 2;
    float4 o4 = make_float4(a0 * inv, a1 * inv, a2 * inv, a3 * inv);
    *(float4*)(out + ((size_t)(b * NDIM + i_glob)) * (HDIM * DDIM) + head * DDIM + dg * 4) = o4;
}

extern "C" void kernel_launch(void* const* d_in, const int* in_sizes, int n_in,
                              void* d_out, int out_size, void* d_ws, size_t ws_size,
                              hipStream_t stream) {
    const float* x       = (const float*)d_in[0];
    const int*   adj     = (const int*)d_in[1];
    const float* W       = (const float*)d_in[2];
    const float* att_src = (const float*)d_in[3];
    const float* att_dst = (const float*)d_in[4];
    float* out = (float*)d_out;

    float* h_ws  = (float*)d_ws;                      // [BH][N][D]  8 MB
    float* es_ws = h_ws + (size_t)BH * NDIM * DDIM;   // [BH][N]   128 KB
    float* ed_ws = es_ws + (size_t)BH * NDIM;         // [BH][N]   128 KB

    gat_linear<<<BDIM * NDIM, 256, 0, stream>>>(x, W, att_src, att_dst, h_ws, es_ws, ed_ws);
    gat_attn<<<BH * (NDIM / TI), 256, 0, stream>>>(adj, h_ws, es_ws, ed_ws, out);
}

// Round 2
// 114.669 us; speedup vs baseline: 3.5640x; 3.5640x over previous
//
#include <hip/hip_runtime.h>

// GAT: B=4, N=2048, IN_DIM=128, H=4, D=64.
// R2: bf16 MFMA for both matmuls.
//  adj_pack:   adj int32 [2048][2048] -> bitmask [2048][64] (512 KB)
//  gat_linear: MFMA GEMM x@W^T -> h_t bf16 [bh][64][2048] (d-major, PV B-operand
//              friendly) + e_src/e_dst fp32 via shuffle-reduced C-frags
//  gat_attn:   per (bh, 64 i-rows): p-gen (exp/mask, fp32->bf16, l_i on the fly)
//              -> LDS A-layout -> MFMA PV vs staged h^T tiles -> normalize.

#define NDIM 2048
#define NEG_SLOPE 0.2f

typedef __bf16 bf16x8 __attribute__((ext_vector_type(8)));
typedef __bf16 bf16x4 __attribute__((ext_vector_type(4)));
typedef float  f32x4  __attribute__((ext_vector_type(4)));

#define LPITCH 136   // 128 + 8 pad (bf16 elems) -> 272B row pitch, 16B aligned
#define APITCH 72    // 64 + 8 pad

// ---------------- adj -> bitmask ----------------
__global__ __launch_bounds__(256) void adj_pack(const int* __restrict__ adj,
                                                unsigned* __restrict__ bits) {
    const int t = threadIdx.x;
    const int q = blockIdx.x * 256 + t;            // int4 index, 2048*2048/4 total
    int4 a = ((const int4*)adj)[q];
    unsigned nib = (unsigned)(a.x > 0) | ((unsigned)(a.y > 0) << 1) |
                   ((unsigned)(a.z > 0) << 2) | ((unsigned)(a.w > 0) << 3);
    unsigned v = nib << ((t & 7) * 4);
    v |= __shfl_xor(v, 1, 64);
    v |= __shfl_xor(v, 2, 64);
    v |= __shfl_xor(v, 4, 64);
    if ((t & 7) == 0) bits[q >> 3] = v;
}

// ---------------- linear: h = x @ W^T (MFMA) + projections ----------------
__global__ __launch_bounds__(256) void gat_linear(
    const float* __restrict__ x, const float* __restrict__ W,
    const float* __restrict__ att_src, const float* __restrict__ att_dst,
    __bf16* __restrict__ h_t, float* __restrict__ es_ws, float* __restrict__ ed_ws)
{
    const int t    = threadIdx.x;
    const int blk  = blockIdx.x;
    const int chh  = blk & 1;                 // column half (128 out-channels)
    const int row0 = (blk >> 1) * 32;         // global row (b*N+n)
    const int b    = row0 >> 11;
    const int n0   = row0 & (NDIM - 1);

    __shared__ __align__(16) __bf16 Wl[128][LPITCH];  // 34.8 KB
    __shared__ __align__(16) __bf16 Xl[32][LPITCH];   //  8.7 KB

    // stage W half (128x128 fp32 -> bf16): 4096 float4 / 256 thr = 16 each
    #pragma unroll 4
    for (int i = 0; i < 16; ++i) {
        int idx = t + i * 256;
        int r = idx >> 5, c4 = idx & 31;
        float4 wv = *((const float4*)(W + (size_t)(chh * 128 + r) * 128) + c4);
        bf16x4 bv;
        bv[0] = (__bf16)wv.x; bv[1] = (__bf16)wv.y; bv[2] = (__bf16)wv.z; bv[3] = (__bf16)wv.w;
        *(bf16x4*)&Wl[r][c4 * 4] = bv;
    }
    // stage x rows (32x128): 1024 float4 / 256 = 4 each
    #pragma unroll
    for (int i = 0; i < 4; ++i) {
        int idx = t + i * 256;
        int r = idx >> 5, c4 = idx & 31;
        float4 xv = *((const float4*)(x + (size_t)(row0 + r) * 128) + c4);
        bf16x4 bv;
        bv[0] = (__bf16)xv.x; bv[1] = (__bf16)xv.y; bv[2] = (__bf16)xv.z; bv[3] = (__bf16)xv.w;
        *(bf16x4*)&Xl[r][c4 * 4] = bv;
    }
    __syncthreads();

    const int lane = t & 63, w = t >> 6;
    const int m = lane & 15, q = lane >> 4;
    const int rt = w & 1;                 // row tile (16 rows)
    const int cb = (w >> 1) * 4;          // first col tile (of 8 in this half)

    bf16x8 af[4];
    #pragma unroll
    for (int ks = 0; ks < 4; ++ks)
        af[ks] = *(const bf16x8*)&Xl[rt * 16 + m][ks * 32 + q * 8];

    f32x4 acc[4];
    #pragma unroll
    for (int c = 0; c < 4; ++c) acc[c] = (f32x4){0.f, 0.f, 0.f, 0.f};

    #pragma unroll
    for (int c = 0; c < 4; ++c) {
        const int ct = cb + c;
        #pragma unroll
        for (int ks = 0; ks < 4; ++ks) {
            bf16x8 bfr = *(const bf16x8*)&Wl[ct * 16 + m][ks * 32 + q * 8];
            acc[c] = __builtin_amdgcn_mfma_f32_16x16x32_bf16(af[ks], bfr, acc[c], 0, 0, 0);
        }
    }

    // epilogue: store h_t (d-major bf16) + dot with att vectors
    const int hh = chh * 2 + (w >> 1);
    const int bh = b * 4 + hh;
    float esA[4] = {0.f, 0.f, 0.f, 0.f}, edA[4] = {0.f, 0.f, 0.f, 0.f};
    #pragma unroll
    for (int c = 0; c < 4; ++c) {
        const int ct   = cb + c;
        const int colg = chh * 128 + ct * 16 + m;   // 0..255
        const int d    = colg & 63;
        const float aS = att_src[colg], aD = att_dst[colg];
        bf16x4 hv;
        #pragma unroll
        for (int r = 0; r < 4; ++r) {
            float v = acc[c][r];
            hv[r] = (__bf16)v;
            esA[r] += v * aS;
            edA[r] += v * aD;
        }
        *(bf16x4*)(h_t + (size_t)(bh * 64 + d) * NDIM + n0 + rt * 16 + q * 4) = hv;
    }
    #pragma unroll
    for (int off = 1; off < 16; off <<= 1) {
        #pragma unroll
        for (int r = 0; r < 4; ++r) {
            esA[r] += __shfl_xor(esA[r], off, 64);
            edA[r] += __shfl_xor(edA[r], off, 64);
        }
    }
    if (m == 0) {
        #pragma unroll
        for (int r = 0; r < 4; ++r) {
            int n = n0 + rt * 16 + q * 4 + r;
            es_ws[bh * NDIM + n] = esA[r];
            ed_ws[bh * NDIM + n] = edA[r];
        }
    }
}

// ---------------- attention: p-gen + MFMA PV ----------------
__global__ __launch_bounds__(256) void gat_attn(
    const unsigned* __restrict__ bits, const __bf16* __restrict__ h_t,
    const float* __restrict__ es_ws, const float* __restrict__ ed_ws,
    float* __restrict__ out)
{
    const int blk = blockIdx.x;
    const int bh  = blk >> 5;
    const int i0  = (blk & 31) * 64;
    const int t   = threadIdx.x;
    const int lane = t & 63, w = t >> 6;
    const int m = lane & 15, q = lane >> 4;

    __shared__ __align__(16) __bf16 Pl[64][APITCH];   // 9.2 KB, A-operand layout
    __shared__ __align__(16) __bf16 Hl[64][APITCH];   // 9.2 KB, h^T tile
    __shared__ float eds[NDIM];                       // 8 KB
    __shared__ float ess[64];
    __shared__ float lred[4][64];
    __shared__ float linv[64];

    {
        const float4* src = (const float4*)(ed_ws + bh * NDIM);
        ((float4*)eds)[t]       = src[t];
        ((float4*)eds)[t + 256] = src[t + 256];
    }
    if (t < 64) ess[t] = es_ws[bh * NDIM + i0 + t];
    __syncthreads();

    const int il = t >> 2;                 // 0..63: p-gen row / h^T d-row
    const int ch = t & 3;                  // 16-wide j chunk
    const float es_i = ess[il];
    const unsigned* brow = bits + (size_t)(i0 + il) * 64;
    const __bf16*   hrow = h_t + (size_t)(bh * 64 + il) * NDIM;

    f32x4 acc[4];
    #pragma unroll
    for (int c = 0; c < 4; ++c) acc[c] = (f32x4){0.f, 0.f, 0.f, 0.f};
    float lacc = 0.f;

    for (int j0 = 0; j0 < NDIM; j0 += 64) {
        // stage h^T tile [64 d][64 j]
        {
            const __bf16* gp = hrow + j0 + ch * 16;
            *(bf16x8*)&Hl[il][ch * 16]     = *(const bf16x8*)gp;
            *(bf16x8*)&Hl[il][ch * 16 + 8] = *(const bf16x8*)(gp + 8);
        }
        // p-gen: 16 elements at row il, cols j0+ch*16..+15
        {
            unsigned word = brow[(j0 >> 5) + (ch >> 1)];
            unsigned bm = (word >> ((ch & 1) * 16)) & 0xFFFFu;
            float ev[16];
            #pragma unroll
            for (int g = 0; g < 4; ++g)
                *(float4*)&ev[g * 4] = *(const float4*)(eds + j0 + ch * 16 + g * 4);
            float pv[16];
            #pragma unroll
            for (int jj = 0; jj < 16; ++jj) {
                float s = es_i + ev[jj];
                s = fmaxf(s, NEG_SLOPE * s);
                float e = __expf(s);
                float p = ((bm >> jj) & 1u) ? e : 0.f;
                pv[jj] = p;
                lacc += p;
            }
            bf16x8 v0, v1;
            #pragma unroll
            for (int jj = 0; jj < 8; ++jj) { v0[jj] = (__bf16)pv[jj]; v1[jj] = (__bf16)pv[jj + 8]; }
            *(bf16x8*)&Pl[il][ch * 16]     = v0;
            *(bf16x8*)&Pl[il][ch * 16 + 8] = v1;
        }
        __syncthreads();

        #pragma unroll
        for (int ks = 0; ks < 2; ++ks) {
            bf16x8 a = *(const bf16x8*)&Pl[w * 16 + m][ks * 32 + q * 8];
            #pragma unroll
            for (int ct = 0; ct < 4; ++ct) {
                bf16x8 bfr = *(const bf16x8*)&Hl[ct * 16 + m][ks * 32 + q * 8];
                acc[ct] = __builtin_amdgcn_mfma_f32_16x16x32_bf16(a, bfr, acc[ct], 0, 0, 0);
            }
        }
        __syncthreads();
    }

    lred[ch][il] = lacc;
    __syncthreads();
    if (t < 64) linv[t] = 1.f / (lred[0][t] + lred[1][t] + lred[2][t] + lred[3][t]);
    __syncthreads();

    const int b_ = bh >> 2, hh = bh & 3;
    float* obase = out + ((size_t)b_ * NDIM + i0) * 256 + hh * 64;
    #pragma unroll
    for (int ct = 0; ct < 4; ++ct) {
        #pragma unroll
        for (int r = 0; r < 4; ++r) {
            int row = w * 16 + q * 4 + r;
            obase[(size_t)row * 256 + ct * 16 + m] = acc[ct][r] * linv[row];
        }
    }
}

extern "C" void kernel_launch(void* const* d_in, const int* in_sizes, int n_in,
                              void* d_out, int out_size, void* d_ws, size_t ws_size,
                              hipStream_t stream) {
    const float* x       = (const float*)d_in[0];
    const int*   adj     = (const int*)d_in[1];
    const float* W       = (const float*)d_in[2];
    const float* att_src = (const float*)d_in[3];
    const float* att_dst = (const float*)d_in[4];
    float* out = (float*)d_out;

    __bf16*   h_t   = (__bf16*)d_ws;                              // 4 MB
    float*    es_ws = (float*)((char*)d_ws + (size_t)4 * 1024 * 1024);
    float*    ed_ws = es_ws + 16 * NDIM;                          // 128 KB each
    unsigned* bitsp = (unsigned*)(ed_ws + 16 * NDIM);             // 512 KB

    adj_pack<<<NDIM * NDIM / 4 / 256, 256, 0, stream>>>(adj, bitsp);
    gat_linear<<<512, 256, 0, stream>>>(x, W, att_src, att_dst, h_t, es_ws, ed_ws);
    gat_attn<<<512, 256, 0, stream>>>(bitsp, h_t, es_ws, ed_ws, out);
}

// Round 3
// 108.599 us; speedup vs baseline: 3.7632x; 1.0559x over previous
//
#include <hip/hip_runtime.h>

// GAT: B=4, N=2048, IN_DIM=128, H=4, D=64.
// R3: register-A p-gen (no P LDS round-trip), Hl double-buffer (1 barrier/iter),
// exp2-folded leaky, swapped-operand linear with n-contiguous h_t stores.

#define NDIM 2048
#define NEG_SLOPE 0.2f
#define LOG2E 1.4426950408889634f

typedef __bf16 bf16x8 __attribute__((ext_vector_type(8)));
typedef __bf16 bf16x4 __attribute__((ext_vector_type(4)));
typedef float  f32x4  __attribute__((ext_vector_type(4)));

#define LP 136   // W/x LDS pitch (bf16): 272 B rows, 16B aligned, quad-spread
#define HP 72    // Hl pitch (bf16): 144 B rows

// ---------------- adj -> bitmask (bit k of word w = adj[w*32+k]) ----------------
__global__ __launch_bounds__(256) void adj_pack(const int* __restrict__ adj,
                                                unsigned* __restrict__ bits) {
    const int t = threadIdx.x;
    const int q = blockIdx.x * 256 + t;            // int4 index
    int4 a = ((const int4*)adj)[q];
    unsigned nib = (unsigned)(a.x > 0) | ((unsigned)(a.y > 0) << 1) |
                   ((unsigned)(a.z > 0) << 2) | ((unsigned)(a.w > 0) << 3);
    unsigned v = nib << ((t & 7) * 4);
    v |= __shfl_xor(v, 1, 64);
    v |= __shfl_xor(v, 2, 64);
    v |= __shfl_xor(v, 4, 64);
    if ((t & 7) == 0) bits[q >> 3] = v;
}

// ---------------- linear: h = x @ W^T (A=W rows -> C rows = out-channel) --------
// grid 512: blk = head(4) x ntile(128 of 64 n). Per block: stage head's W quarter
// (64x128) + 64 x-rows. Wave w -> n cols w*16+m. C[o][n]: o = ct*16+q*4+r, n = m.
__global__ __launch_bounds__(256) void gat_linear(
    const float* __restrict__ x, const float* __restrict__ W,
    const float* __restrict__ att_src, const float* __restrict__ att_dst,
    __bf16* __restrict__ h_t, float* __restrict__ es_ws, float* __restrict__ ed_ws)
{
    const int t    = threadIdx.x;
    const int head = blockIdx.x & 3;
    const int n0g  = (blockIdx.x >> 2) * 64;       // global row in [0, 8192)
    const int b    = n0g >> 11;
    const int n0   = n0g & (NDIM - 1);
    const int bh   = b * 4 + head;

    __shared__ __align__(16) __bf16 Wl[64][LP];    // 17.4 KB
    __shared__ __align__(16) __bf16 Xl[64][LP];    // 17.4 KB

    // stage W quarter (64x128 fp32 -> bf16): 2048 float4 / 256 = 8 each
    #pragma unroll
    for (int i = 0; i < 8; ++i) {
        int idx = t + i * 256;
        int r = idx >> 5, c4 = idx & 31;
        float4 wv = *((const float4*)(W + (size_t)(head * 64 + r) * 128) + c4);
        bf16x4 bv;
        bv[0] = (__bf16)wv.x; bv[1] = (__bf16)wv.y; bv[2] = (__bf16)wv.z; bv[3] = (__bf16)wv.w;
        *(bf16x4*)&Wl[r][c4 * 4] = bv;
    }
    // stage x rows (64x128)
    #pragma unroll
    for (int i = 0; i < 8; ++i) {
        int idx = t + i * 256;
        int r = idx >> 5, c4 = idx & 31;
        float4 xv = *((const float4*)(x + (size_t)(n0g + r) * 128) + c4);
        bf16x4 bv;
        bv[0] = (__bf16)xv.x; bv[1] = (__bf16)xv.y; bv[2] = (__bf16)xv.z; bv[3] = (__bf16)xv.w;
        *(bf16x4*)&Xl[r][c4 * 4] = bv;
    }
    __syncthreads();

    const int lane = t & 63, w = t >> 6;
    const int m = lane & 15, q4 = lane >> 4;

    bf16x8 bfr[4];
    #pragma unroll
    for (int ks = 0; ks < 4; ++ks)
        bfr[ks] = *(const bf16x8*)&Xl[w * 16 + m][ks * 32 + q4 * 8];

    f32x4 acc[4];
    #pragma unroll
    for (int c = 0; c < 4; ++c) acc[c] = (f32x4){0.f, 0.f, 0.f, 0.f};

    #pragma unroll
    for (int ct = 0; ct < 4; ++ct) {
        #pragma unroll
        for (int ks = 0; ks < 4; ++ks) {
            bf16x8 afr = *(const bf16x8*)&Wl[ct * 16 + m][ks * 32 + q4 * 8];
            acc[ct] = __builtin_amdgcn_mfma_f32_16x16x32_bf16(afr, bfr[ks], acc[ct], 0, 0, 0);
        }
    }

    // epilogue: h_t[bh][d][n] (n-contiguous) + es/ed reductions over d
    const int nloc = n0 + w * 16 + m;
    float esA = 0.f, edA = 0.f;
    #pragma unroll
    for (int ct = 0; ct < 4; ++ct) {
        float4 aS = *(const float4*)(att_src + head * 64 + ct * 16 + q4 * 4);
        float4 aD = *(const float4*)(att_dst + head * 64 + ct * 16 + q4 * 4);
        #pragma unroll
        for (int r = 0; r < 4; ++r) {
            float v = acc[ct][r];
            int   d = ct * 16 + q4 * 4 + r;
            h_t[(size_t)(bh * 64 + d) * NDIM + nloc] = (__bf16)v;
            esA += v * ((const float*)&aS)[r];
            edA += v * ((const float*)&aD)[r];
        }
    }
    esA += __shfl_xor(esA, 16, 64); esA += __shfl_xor(esA, 32, 64);
    edA += __shfl_xor(edA, 16, 64); edA += __shfl_xor(edA, 32, 64);
    if (lane < 16) {
        es_ws[bh * NDIM + nloc] = esA;
        ed_ws[bh * NDIM + nloc] = edA;
    }
}

// ---------------- attention: register-A p-gen + MFMA PV, Hl dbuf ----------------
// grid 512: bh = blk & 15 (same-bh blocks share low-3 bits -> same XCD-ish),
// it = blk >> 4. Wave w owns i-rows i0+w*16+m (A rows). 32 j-tiles of 64.
__global__ __launch_bounds__(256) void gat_attn(
    const unsigned long long* __restrict__ bits, const __bf16* __restrict__ h_t,
    const float* __restrict__ es_ws, const float* __restrict__ ed_ws,
    float* __restrict__ out)
{
    const int blk = blockIdx.x;
    const int bh  = blk & 15;
    const int i0  = (blk >> 4) * 64;
    const int t   = threadIdx.x;
    const int lane = t & 63, w = t >> 6;
    const int m = lane & 15, q4 = lane >> 4;
    const int il = t >> 2;                 // staging d-row 0..63
    const int ch = t & 3;                  // staging col group (16 elems)

    __shared__ __align__(16) __bf16 Hl[2][64][HP];   // 18.4 KB
    __shared__ float eds[NDIM];                      // 8 KB, pre-scaled by log2e

    // stage e_dst * log2e
    #pragma unroll
    for (int k = 0; k < 2; ++k) {
        int idx = t + k * 256;
        float4 v = ((const float4*)(ed_ws + bh * NDIM))[idx];
        v.x *= LOG2E; v.y *= LOG2E; v.z *= LOG2E; v.w *= LOG2E;
        ((float4*)eds)[idx] = v;
    }
    const float es2 = es_ws[bh * NDIM + i0 + w * 16 + m] * LOG2E;
    const unsigned long long* brow = bits + (size_t)(i0 + w * 16 + m) * 32;

    const __bf16* hbase = h_t + (size_t)(bh * 64 + il) * NDIM + ch * 16;
    // preload tile 0
    {
        bf16x8 c0 = *(const bf16x8*)hbase;
        bf16x8 c1 = *(const bf16x8*)(hbase + 8);
        *(bf16x8*)&Hl[0][il][ch * 16]     = c0;
        *(bf16x8*)&Hl[0][il][ch * 16 + 8] = c1;
    }
    __syncthreads();

    f32x4 acc[4];
    #pragma unroll
    for (int c = 0; c < 4; ++c) acc[c] = (f32x4){0.f, 0.f, 0.f, 0.f};
    float lacc = 0.f;

    for (int itj = 0; itj < 32; ++itj) {
        const int buf = itj & 1;
        const bool hn = itj < 31;
        bf16x8 n0v, n1v;
        if (hn) {   // next tile's global loads in flight across p-gen + MFMA
            const __bf16* gp = hbase + (itj + 1) * 64;
            n0v = *(const bf16x8*)gp;
            n1v = *(const bf16x8*)(gp + 8);
        }

        const unsigned long long bw = brow[itj];
        const int j0 = itj * 64;
        bf16x8 af[2];
        #pragma unroll
        for (int ks = 0; ks < 2; ++ks) {
            float e[8];
            *(float4*)&e[0] = *(const float4*)&eds[j0 + ks * 32 + q4 * 8];
            *(float4*)&e[4] = *(const float4*)&eds[j0 + ks * 32 + q4 * 8 + 4];
            unsigned bm = (unsigned)(bw >> (ks * 32 + q4 * 8)) & 0xFFu;
            #pragma unroll
            for (int jj = 0; jj < 8; ++jj) {
                float s = es2 + e[jj];                     // already *log2e
                s = fmaxf(s, NEG_SLOPE * s);               // leaky (homogeneous)
                s = ((bm >> jj) & 1u) ? s : -10000.0f;     // exp2(-1e4) == 0
                float p = __builtin_amdgcn_exp2f(s);
                lacc += p;
                af[ks][jj] = (__bf16)p;
            }
        }

        #pragma unroll
        for (int ks = 0; ks < 2; ++ks) {
            #pragma unroll
            for (int ct = 0; ct < 4; ++ct) {
                bf16x8 bfr = *(const bf16x8*)&Hl[buf][ct * 16 + m][ks * 32 + q4 * 8];
                acc[ct] = __builtin_amdgcn_mfma_f32_16x16x32_bf16(af[ks], bfr, acc[ct], 0, 0, 0);
            }
        }

        if (hn) {
            *(bf16x8*)&Hl[buf ^ 1][il][ch * 16]     = n0v;
            *(bf16x8*)&Hl[buf ^ 1][il][ch * 16 + 8] = n1v;
        }
        __syncthreads();
    }

    // l: sum over q4-lanes of row m, then fetch per output row q*4+r
    lacc += __shfl_xor(lacc, 16, 64);
    lacc += __shfl_xor(lacc, 32, 64);
    const float inv = 1.f / lacc;          // lane (m, q4) holds inv for row m
    float invr[4];
    #pragma unroll
    for (int r = 0; r < 4; ++r) invr[r] = __shfl(inv, q4 * 4 + r, 64);

    const int b = bh >> 2, head = bh & 3;
    float* ob = out + ((size_t)(b * NDIM + i0 + w * 16)) * 256 + head * 64;
    #pragma unroll
    for (int ct = 0; ct < 4; ++ct) {
        #pragma unroll
        for (int r = 0; r < 4; ++r) {
            ob[(size_t)(q4 * 4 + r) * 256 + ct * 16 + m] = acc[ct][r] * invr[r];
        }
    }
}

extern "C" void kernel_launch(void* const* d_in, const int* in_sizes, int n_in,
                              void* d_out, int out_size, void* d_ws, size_t ws_size,
                              hipStream_t stream) {
    const float* x       = (const float*)d_in[0];
    const int*   adj     = (const int*)d_in[1];
    const float* W       = (const float*)d_in[2];
    const float* att_src = (const float*)d_in[3];
    const float* att_dst = (const float*)d_in[4];
    float* out = (float*)d_out;

    __bf16*   h_t   = (__bf16*)d_ws;                              // 4 MB
    float*    es_ws = (float*)((char*)d_ws + (size_t)4 * 1024 * 1024);
    float*    ed_ws = es_ws + 16 * NDIM;                          // 128 KB each
    unsigned* bitsp = (unsigned*)(ed_ws + 16 * NDIM);             // 512 KB

    adj_pack<<<NDIM * NDIM / 4 / 256, 256, 0, stream>>>(adj, bitsp);
    gat_linear<<<512, 256, 0, stream>>>(x, W, att_src, att_dst, h_t, es_ws, ed_ws);
    gat_attn<<<512, 256, 0, stream>>>((const unsigned long long*)bitsp, h_t, es_ws, ed_ws, out);
}

// Round 4
// 107.604 us; speedup vs baseline: 3.7980x; 1.0093x over previous
//
#include <hip/hip_runtime.h>

// GAT: B=4, N=2048, IN_DIM=128, H=4, D=64.
// R4: attn staging via global_load_lds (16B DMA, XOR-swizzled Hl), l-row sums
// via ones-column MFMA (no lacc, no end shuffles), eds from registers
// (prefetched, pre-scaled by log2e in the linear epilogue).

#define NDIM 2048
#define NEG_SLOPE 0.2f
#define LOG2E 1.4426950408889634f

typedef __bf16 bf16x8 __attribute__((ext_vector_type(8)));
typedef __bf16 bf16x4 __attribute__((ext_vector_type(4)));
typedef float  f32x4  __attribute__((ext_vector_type(4)));

#define LP 136   // linear LDS pitch (bf16)

__device__ static inline void load_lds16(const void* g, void* l) {
    __builtin_amdgcn_global_load_lds(
        (const __attribute__((address_space(1))) unsigned*)g,
        (__attribute__((address_space(3))) unsigned*)l, 16, 0, 0);
}

// ---------------- adj -> bitmask (bit k of word w = adj[w*32+k]) ----------------
__global__ __launch_bounds__(256) void adj_pack(const int* __restrict__ adj,
                                                unsigned* __restrict__ bits) {
    const int t = threadIdx.x;
    const int q = blockIdx.x * 256 + t;            // int4 index
    int4 a = ((const int4*)adj)[q];
    unsigned nib = (unsigned)(a.x > 0) | ((unsigned)(a.y > 0) << 1) |
                   ((unsigned)(a.z > 0) << 2) | ((unsigned)(a.w > 0) << 3);
    unsigned v = nib << ((t & 7) * 4);
    v |= __shfl_xor(v, 1, 64);
    v |= __shfl_xor(v, 2, 64);
    v |= __shfl_xor(v, 4, 64);
    if ((t & 7) == 0) bits[q >> 3] = v;
}

// ---------------- linear: h = x @ W^T (A=W rows -> C rows = out-channel) --------
__global__ __launch_bounds__(256) void gat_linear(
    const float* __restrict__ x, const float* __restrict__ W,
    const float* __restrict__ att_src, const float* __restrict__ att_dst,
    __bf16* __restrict__ h_t, float* __restrict__ es_ws, float* __restrict__ ed_ws)
{
    const int t    = threadIdx.x;
    const int head = blockIdx.x & 3;
    const int n0g  = (blockIdx.x >> 2) * 64;       // global row in [0, 8192)
    const int b    = n0g >> 11;
    const int n0   = n0g & (NDIM - 1);
    const int bh   = b * 4 + head;

    __shared__ __align__(16) __bf16 Wl[64][LP];    // 17.4 KB
    __shared__ __align__(16) __bf16 Xl[64][LP];    // 17.4 KB

    #pragma unroll
    for (int i = 0; i < 8; ++i) {
        int idx = t + i * 256;
        int r = idx >> 5, c4 = idx & 31;
        float4 wv = *((const float4*)(W + (size_t)(head * 64 + r) * 128) + c4);
        bf16x4 bv;
        bv[0] = (__bf16)wv.x; bv[1] = (__bf16)wv.y; bv[2] = (__bf16)wv.z; bv[3] = (__bf16)wv.w;
        *(bf16x4*)&Wl[r][c4 * 4] = bv;
    }
    #pragma unroll
    for (int i = 0; i < 8; ++i) {
        int idx = t + i * 256;
        int r = idx >> 5, c4 = idx & 31;
        float4 xv = *((const float4*)(x + (size_t)(n0g + r) * 128) + c4);
        bf16x4 bv;
        bv[0] = (__bf16)xv.x; bv[1] = (__bf16)xv.y; bv[2] = (__bf16)xv.z; bv[3] = (__bf16)xv.w;
        *(bf16x4*)&Xl[r][c4 * 4] = bv;
    }
    __syncthreads();

    const int lane = t & 63, w = t >> 6;
    const int m = lane & 15, q4 = lane >> 4;

    bf16x8 bfr[4];
    #pragma unroll
    for (int ks = 0; ks < 4; ++ks)
        bfr[ks] = *(const bf16x8*)&Xl[w * 16 + m][ks * 32 + q4 * 8];

    f32x4 acc[4];
    #pragma unroll
    for (int c = 0; c < 4; ++c) acc[c] = (f32x4){0.f, 0.f, 0.f, 0.f};

    #pragma unroll
    for (int ct = 0; ct < 4; ++ct) {
        #pragma unroll
        for (int ks = 0; ks < 4; ++ks) {
            bf16x8 afr = *(const bf16x8*)&Wl[ct * 16 + m][ks * 32 + q4 * 8];
            acc[ct] = __builtin_amdgcn_mfma_f32_16x16x32_bf16(afr, bfr[ks], acc[ct], 0, 0, 0);
        }
    }

    // epilogue: h_t[bh][d][n] (n-contiguous) + es/ed reductions over d
    const int nloc = n0 + w * 16 + m;
    float esA = 0.f, edA = 0.f;
    #pragma unroll
    for (int ct = 0; ct < 4; ++ct) {
        float4 aS = *(const float4*)(att_src + head * 64 + ct * 16 + q4 * 4);
        float4 aD = *(const float4*)(att_dst + head * 64 + ct * 16 + q4 * 4);
        #pragma unroll
        for (int r = 0; r < 4; ++r) {
            float v = acc[ct][r];
            int   d = ct * 16 + q4 * 4 + r;
            h_t[(size_t)(bh * 64 + d) * NDIM + nloc] = (__bf16)v;
            esA += v * ((const float*)&aS)[r];
            edA += v * ((const float*)&aD)[r];
        }
    }
    esA += __shfl_xor(esA, 16, 64); esA += __shfl_xor(esA, 32, 64);
    edA += __shfl_xor(edA, 16, 64); edA += __shfl_xor(edA, 32, 64);
    if (lane < 16) {
        es_ws[bh * NDIM + nloc] = esA * LOG2E;   // pre-scaled: exp2 domain
        ed_ws[bh * NDIM + nloc] = edA * LOG2E;
    }
}

// ---------------- attention: DMA-staged Hl + register p-gen + MFMA PV ----------
// grid 512: bh = blk & 15, it = blk >> 4. Wave w owns A-rows i0+w*16+m.
// Hl[buf][d][64] bf16, XOR-swizzled: chunk c8 of row d holds j-chunk (c8 ^ (d&7)).
__global__ __launch_bounds__(256) void gat_attn(
    const unsigned long long* __restrict__ bits, const __bf16* __restrict__ h_t,
    const float* __restrict__ es_ws, const float* __restrict__ ed_ws,
    float* __restrict__ out)
{
    const int blk = blockIdx.x;
    const int bh  = blk & 15;
    const int i0  = (blk >> 4) * 64;
    const int t   = threadIdx.x;
    const int lane = t & 63, w = t >> 6;
    const int m = lane & 15, q4 = lane >> 4;

    __shared__ __align__(16) __bf16 Hl[2][64][64];   // 16 KB

    // DMA lanes: wave w stages rows w*16..w*16+15 (2 chunks of 8 rows)
    const int r0 = w * 16 + (lane >> 3);
    const int r1 = r0 + 8;
    const int c8 = lane & 7;
    const __bf16* g0 = h_t + ((size_t)(bh * 64 + r0)) * NDIM + ((c8 ^ (r0 & 7)) * 8);
    const __bf16* g1 = h_t + ((size_t)(bh * 64 + r1)) * NDIM + ((c8 ^ (r1 & 7)) * 8);
    __bf16* l0a = &Hl[0][r0][c8 * 8];
    __bf16* l0b = &Hl[0][r1][c8 * 8];
    __bf16* l1a = &Hl[1][r0][c8 * 8];
    __bf16* l1b = &Hl[1][r1][c8 * 8];

    const float es2 = es_ws[bh * NDIM + i0 + w * 16 + m];       // *log2e already
    const unsigned long long* brow = bits + (size_t)(i0 + w * 16 + m) * 32;
    const float* edp = ed_ws + bh * NDIM + q4 * 8;              // *log2e already

    // preload tile 0: DMA + scalar prefetch
    load_lds16(g0, l0a);
    load_lds16(g1, l0b);
    float eb[2][16];
    unsigned long long bwb[2];
    #pragma unroll
    for (int g = 0; g < 4; ++g)
        *(float4*)&eb[0][g * 4] = *(const float4*)(edp + (g >> 1) * 32 + (g & 1) * 4);
    bwb[0] = brow[0];

    f32x4 acc[4], accl;
    #pragma unroll
    for (int c = 0; c < 4; ++c) acc[c] = (f32x4){0.f, 0.f, 0.f, 0.f};
    accl = (f32x4){0.f, 0.f, 0.f, 0.f};
    bf16x8 ones;
    #pragma unroll
    for (int jj = 0; jj < 8; ++jj) ones[jj] = (__bf16)1.0f;
    const int sw = m & 7;

    __syncthreads();    // drains tile-0 DMA

#define STEP(ITJ, P)                                                            \
    {                                                                           \
        const int itj = (ITJ);                                                  \
        if (itj < 31) {                                                         \
            load_lds16(g0 + (itj + 1) * 64, (P) ? l0a : l1a);                   \
            load_lds16(g1 + (itj + 1) * 64, (P) ? l0b : l1b);                   \
            const float* ep = edp + (itj + 1) * 64;                             \
            _Pragma("unroll")                                                   \
            for (int g = 0; g < 4; ++g)                                         \
                *(float4*)&eb[(P) ^ 1][g * 4] =                                 \
                    *(const float4*)(ep + (g >> 1) * 32 + (g & 1) * 4);         \
            bwb[(P) ^ 1] = brow[itj + 1];                                       \
        }                                                                       \
        bf16x8 af[2];                                                           \
        _Pragma("unroll")                                                       \
        for (int ks = 0; ks < 2; ++ks) {                                        \
            unsigned bm = (unsigned)(bwb[P] >> (ks * 32 + q4 * 8)) & 0xFFu;     \
            _Pragma("unroll")                                                   \
            for (int jj = 0; jj < 8; ++jj) {                                    \
                float s = es2 + eb[P][ks * 8 + jj];                             \
                s = fmaxf(s, NEG_SLOPE * s);                                    \
                s = ((bm >> jj) & 1u) ? s : -10000.0f;                          \
                af[ks][jj] = (__bf16)__builtin_amdgcn_exp2f(s);                 \
            }                                                                   \
        }                                                                       \
        _Pragma("unroll")                                                       \
        for (int ks = 0; ks < 2; ++ks) {                                        \
            accl = __builtin_amdgcn_mfma_f32_16x16x32_bf16(af[ks], ones, accl, 0, 0, 0); \
            _Pragma("unroll")                                                   \
            for (int ct = 0; ct < 4; ++ct) {                                    \
                bf16x8 bfr = *(const bf16x8*)&Hl[P][ct * 16 + m][(((ks * 4 + q4) ^ sw)) * 8]; \
                acc[ct] = __builtin_amdgcn_mfma_f32_16x16x32_bf16(af[ks], bfr, acc[ct], 0, 0, 0); \
            }                                                                   \
        }                                                                       \
        __syncthreads();                                                        \
    }

    for (int it2 = 0; it2 < 16; ++it2) {
        STEP(it2 * 2, 0);
        STEP(it2 * 2 + 1, 1);
    }
#undef STEP

    // accl[r] = l for output row q4*4+r (all m-lanes identical) — no shuffles
    float invr[4];
    #pragma unroll
    for (int r = 0; r < 4; ++r) invr[r] = 1.f / accl[r];

    const int b = bh >> 2, head = bh & 3;
    float* ob = out + ((size_t)(b * NDIM + i0 + w * 16)) * 256 + head * 64;
    #pragma unroll
    for (int ct = 0; ct < 4; ++ct) {
        #pragma unroll
        for (int r = 0; r < 4; ++r) {
            ob[(size_t)(q4 * 4 + r) * 256 + ct * 16 + m] = acc[ct][r] * invr[r];
        }
    }
}

extern "C" void kernel_launch(void* const* d_in, const int* in_sizes, int n_in,
                              void* d_out, int out_size, void* d_ws, size_t ws_size,
                              hipStream_t stream) {
    const float* x       = (const float*)d_in[0];
    const int*   adj     = (const int*)d_in[1];
    const float* W       = (const float*)d_in[2];
    const float* att_src = (const float*)d_in[3];
    const float* att_dst = (const float*)d_in[4];
    float* out = (float*)d_out;

    __bf16*   h_t   = (__bf16*)d_ws;                              // 4 MB
    float*    es_ws = (float*)((char*)d_ws + (size_t)4 * 1024 * 1024);
    float*    ed_ws = es_ws + 16 * NDIM;                          // 128 KB each
    unsigned* bitsp = (unsigned*)(ed_ws + 16 * NDIM);             // 512 KB

    adj_pack<<<NDIM * NDIM / 4 / 256, 256, 0, stream>>>(adj, bitsp);
    gat_linear<<<512, 256, 0, stream>>>(x, W, att_src, att_dst, h_t, es_ws, ed_ws);
    gat_attn<<<512, 256, 0, stream>>>((const unsigned long long*)bitsp, h_t, es_ws, ed_ws, out);
}